// Round 3
// baseline (317.202 us; speedup 1.0000x reference)
//
#include <hip/hip_runtime.h>
#include <math.h>

namespace {
constexpr float TAU      = 0.05f;
constexpr float EPS_SUM  = 1e-8f;
constexpr float EPS_LOG  = 1e-10f;
constexpr int   BLOCK    = 256;
constexpr int   GRID     = 2048;
}

// Sum x across the 4 lanes of a quad via DPP quad_perm (VALU pipe, no LDS).
__device__ inline float quad_sum(float x) {
    int a = __builtin_amdgcn_mov_dpp(__float_as_int(x), 0xB1, 0xF, 0xF, true);
    x += __int_as_float(a);
    a = __builtin_amdgcn_mov_dpp(__float_as_int(x), 0x4E, 0xF, 0xF, true);
    x += __int_as_float(a);
    return x;
}

// 4 lanes per belief row. Restructured math:
//   l_j   = log2(c_j + eps*S)            (exact: log2(p_j+eps) = l_j - log2 S)
//   Hpr   = log2S - (1/S) * sum c_j l_j
//   Hpo   = log2T - (1/T) * (sum c_j l_j + (c_b+1)*lb1 - c_b*l_b)
//   ig    = max(log2S - log2T + ((c_b+1)/T)*(lb1 - l_b), 0)
// -> one log per element + 3 row logs, vs 2 logs/element before.
__global__ __launch_bounds__(BLOCK) void ev_main(
    const float* __restrict__ obs,          // (8, dim)
    const float* __restrict__ belief,       // (dim, 16)
    float* __restrict__ out_info,           // (dim,)
    float* __restrict__ out_Hprior,         // (dim,)
    float* __restrict__ out_Hpost,          // (dim,)
    float* __restrict__ out_newbelief,      // (dim,16) slice, 8B-aligned only
    float* __restrict__ ws_partials,        // (GRID,)
    int dim)
{
    const int tid    = blockIdx.x * BLOCK + threadIdx.x;
    const int stride = BLOCK * GRID;
    const int W      = dim * 4;
    float local_sum = 0.0f;                 // 4x per row; divided out later

    const float4* belief4 = reinterpret_cast<const float4*>(belief);
    float2* nb2 = reinterpret_cast<float2*>(out_newbelief);

#pragma unroll 2
    for (int f = tid; f < W; f += stride) {
        const int r = f >> 2;
        const int m = f & 3;

        float4 c4 = belief4[f];             // coalesced 16B/lane
        float cc[4] = {c4.x, c4.y, c4.z, c4.w};
        float cs = (cc[0] + cc[1]) + (cc[2] + cc[3]);
        float os = obs[(size_t)(2 * m) * dim + r]
                 + obs[(size_t)(2 * m + 1) * dim + r];

        cs = quad_sum(cs);                  // S (row count-sum)
        os = quad_sum(os);                  // sum of 8 obs values
        float om = os * 0.125f;

        // sigmoid -> bin (keep precise: bin boundaries must match reference)
        float sig = 1.0f / (1.0f + expf(-om));
        int bin = (int)(sig * 15.0f);
        bin = bin < 0 ? 0 : (bin > 15 ? 15 : bin);

        const float S = fmaxf(cs, EPS_SUM);
        const float T = fmaxf(cs + 1.0f, EPS_SUM);
        const float invS = __builtin_amdgcn_rcpf(S);
        const float invT = __builtin_amdgcn_rcpf(T);
        const float epsS = EPS_LOG * S;
        const float epsT = EPS_LOG * T;

        // per-element: one log, one FMA into A, EMA update
        float l[4], nb[4];
        float A_part = 0.0f;
        const int j0 = m * 4;
#pragma unroll
        for (int e = 0; e < 4; ++e) {
            float cj = cc[e];
            l[e] = log2f(cj + epsS);
            A_part = fmaf(cj, l[e], A_part);
            float oh = (j0 + e == bin) ? TAU : 0.0f;
            nb[e] = fmaxf(fmaf(cj, 1.0f - TAU, oh), 0.01f);
        }

        // bin-owner correction terms (one extra log)
        const bool own = (bin >> 2) == m;
        const int  bl  = bin & 3;
        float cb  = cc[bl];
        float lb  = l[bl];
        float lb1 = log2f(cb + 1.0f + epsT);
        float bterm = own ? fmaf(cb + 1.0f, lb1, -cb * lb) : 0.0f;
        float igb   = own ? (cb + 1.0f) * invT * (lb1 - lb) : 0.0f;

        float A = quad_sum(A_part);
        bterm   = quad_sum(bterm);
        igb     = quad_sum(igb);

        float log2S = log2f(S);
        float log2T = log2f(T);
        float Hpr = log2S - invS * A;
        float Hpo = log2T - invT * (A + bterm);
        float ig  = fmaxf(log2S - log2T + igb, 0.0f);
        local_sum += ig;

        if (m == 0) {
            out_info[r]   = ig;
            out_Hprior[r] = Hpr;
            out_Hpost[r]  = Hpo;
        }

        nb2[(size_t)f * 2]     = make_float2(nb[0], nb[1]);
        nb2[(size_t)f * 2 + 1] = make_float2(nb[2], nb[3]);
    }

    __shared__ float sdata[BLOCK];
    sdata[threadIdx.x] = local_sum;
    __syncthreads();
#pragma unroll
    for (int off = BLOCK / 2; off > 0; off >>= 1) {
        if (threadIdx.x < off) sdata[threadIdx.x] += sdata[threadIdx.x + off];
        __syncthreads();
    }
    if (threadIdx.x == 0) ws_partials[blockIdx.x] = sdata[0];
}

__global__ __launch_bounds__(BLOCK) void ev_finalize(
    const float* __restrict__ ws_partials,
    float* __restrict__ out_mean,
    float* __restrict__ out_epi,
    int n_partials, float inv_cnt)
{
    float s = 0.0f;
    for (int i = threadIdx.x; i < n_partials; i += BLOCK) s += ws_partials[i];
    __shared__ float sdata[BLOCK];
    sdata[threadIdx.x] = s;
    __syncthreads();
#pragma unroll
    for (int off = BLOCK / 2; off > 0; off >>= 1) {
        if (threadIdx.x < off) sdata[threadIdx.x] += sdata[threadIdx.x + off];
        __syncthreads();
    }
    if (threadIdx.x == 0) {
        float mean = sdata[0] * inv_cnt;
        *out_mean = mean;
        *out_epi  = 1.0f / (1.0f + expf(-(mean * 50.0f - 1.0f)));
    }
}

extern "C" void kernel_launch(void* const* d_in, const int* in_sizes, int n_in,
                              void* d_out, int out_size, void* d_ws, size_t ws_size,
                              hipStream_t stream)
{
    const float* obs    = (const float*)d_in[0];   // (8, dim) fp32
    const float* belief = (const float*)d_in[1];   // (dim, 16) fp32
    const int dim = in_sizes[0] / 8;

    float* o             = (float*)d_out;
    float* out_info      = o;
    float* out_mean      = o + dim;
    float* out_Hprior    = o + dim + 1;
    float* out_Hpost     = o + 2 * (size_t)dim + 1;
    float* out_epi       = o + 3 * (size_t)dim + 1;
    float* out_newbelief = o + 3 * (size_t)dim + 2;

    float* partials = (float*)d_ws;

    ev_main<<<GRID, BLOCK, 0, stream>>>(obs, belief, out_info, out_Hprior,
                                        out_Hpost, out_newbelief, partials, dim);
    ev_finalize<<<1, BLOCK, 0, stream>>>(partials, out_mean, out_epi, GRID,
                                         1.0f / (4.0f * (float)dim));
}